// Round 16
// baseline (22.404 us; speedup 1.0000x reference)
//
#include <hip/hip_runtime.h>
#include <math.h>

#define BB 32
#define II 512
#define OO 512
#define NN 16

#define NW 2              // n-window: the two nearest centers (lo = floor(nc))
#define LOMAX (NN - NW)   // 14
#define OPB 4             // o's per block -> 256 B param segments (>=128 B: saturated lever)
#define CHI 16            // i's per TILE
#define TPB 2             // tiles per block, i-direction (reg-prefetch pipeline)
#define QP (II / (CHI * TPB))   // 16 -> ws = QP*OO*BB floats = 1 MB
#define NOB (OO / OPB)    // 128; grid = QP*NOB = 2048
#define XP 33             // xs pitch for 32 i's (odd -> conflict-free)

#if __has_builtin(__builtin_amdgcn_exp2f)
#define EXP2F(x) __builtin_amdgcn_exp2f(x)
#else
#define EXP2F(x) exp2f(x)
#endif
#if __has_builtin(__builtin_amdgcn_rcpf)
#define RCPF(x) __builtin_amdgcn_rcpf(x)
#else
#define RCPF(x) (1.0f / (x))
#endif

#define KS      1.2011224087f
#define K_A2N   0.5887050112f
// A&S 7.1.27: erf(x) = 1 - (1 + a1 x + a2 x^2 + a3 x^3 + a4 x^4)^-4, |err|<=5e-4
#define EA1 0.278393f
#define EA2 0.230389f
#define EA3 0.000972f
#define EA4 0.078108f

// R15 + T14-style async-STAGE pipeline: each block owns TWO i-tiles.
// tile1's param loads are ISSUED (global->reg) right after the first
// barrier and consumed after compute(tile0) — the ~900cy HBM latency
// hides under tile0's ~900cy compute. pr LDS is single-buffered (16 KB),
// reused across tiles with a barrier fence. acc accumulates over both
// tiles -> ws back to 1 MB, reduce work halved. Body math, window,
// staging addresses: unchanged (absmax 2.44e-4 lineage).
__global__ __launch_bounds__(256, 6)
void kat_win(const float* __restrict__ x,
             const float* __restrict__ mx_train,
             const float* __restrict__ scale,
             const float* __restrict__ sigma,
             const float* __restrict__ alpha,
             const float* __restrict__ w,
             const float* __restrict__ mx_start,
             float* __restrict__ ws)
{
    __shared__ float4 pr[CHI * OPB * NN];   // 16 KB [ii][op][n], reused per tile
    __shared__ float  xs[BB * XP];          // 4.2 KB [b][ii], 32 i's
    __shared__ float2 sc[TPB][CHI * OPB];   // 1 KB
    __shared__ float  red[OPB][8][BB];      // 4 KB

    const int bid   = blockIdx.x;
    const int ob    = bid & (NOB - 1);
    const int qp    = bid >> 7;             // NOB = 128
    const int o0    = ob * OPB;
    const int ibase = qp * (CHI * TPB);     // 32 i's
    const int tid   = threadIdx.x;
    const int b     = tid & 31;
    const int iw    = tid >> 5;             // 0..7

    // staging assignment (same for both tiles): 16 float4 = 256 B per i-row
    const int il   = tid >> 4;              // 0..15
    const int r    = tid & 15;
    const int op_s = r >> 2;                // 0..3
    const int n0   = (r & 3) * 4;           // 0,4,8,12
    const int io0  = (ibase + il) * OO + o0 + op_s;
    const int io1  = io0 + CHI * OO;

    const float4 mx4 = *reinterpret_cast<const float4*>(&mx_start[n0]);

    // ---- issue + consume tile0 param loads ----
    const float4 sgA  = *reinterpret_cast<const float4*>(&sigma[io0 * NN + n0]);
    const float4 alA  = *reinterpret_cast<const float4*>(&alpha[io0 * NN + n0]);
    const float4 wA   = *reinterpret_cast<const float4*>(&w[io0 * NN + n0]);
    const float  scaA = scale[io0];
    const float  mxtA = mx_train[io0];

    // ---- stage x[b][ibase+ii] (32 i's, coalesced) ----
#pragma unroll
    for (int p = 0; p < (BB * 32) / 256; ++p) {   // 4 iters
        const int idx = p * 256 + tid;
        const int bb  = idx >> 5;
        const int ii  = idx & 31;
        xs[bb * XP + ii] = x[bb * II + ibase + ii];
    }
    // ---- stage window coefs for both tiles ----
    if (tid < TPB * CHI * OPB) {            // 128
        const int t  = tid >> 6;
        const int ii = (tid >> 2) & 15;
        const int op = tid & 3;
        const int io = (ibase + t * CHI + ii) * OO + o0 + op;
        const float s   = fmaxf(fabsf(scale[io]), 1e-20f);
        const float inv = 15.0f * RCPF(s);
        sc[t][ii * OPB + op] = make_float2(inv, -mx_train[io] * inv);
    }

    // ---- transform tile0 -> pr ----
    {
        const float sg[4] = {sgA.x, sgA.y, sgA.z, sgA.w};
        const float al[4] = {alA.x, alA.y, alA.z, alA.w};
        const float wv[4] = {wA.x,  wA.y,  wA.z,  wA.w};
        const float mx[4] = {mx4.x, mx4.y, mx4.z, mx4.w};
        const float sa = fabsf(scaA);
        float4* dst = &pr[(il * OPB + op_s) * NN + n0];
#pragma unroll
        for (int c = 0; c < 4; ++c) {
            const float c1s = KS * RCPF(fabsf(sg[c]) + 1e-8f);
            const float ctr = fmaf(sa, mx[c], mxtA);
            dst[c] = make_float4(c1s, -ctr * c1s, al[c] * K_A2N, wv[c]);
        }
    }
    __syncthreads();

    // ---- ISSUE tile1 loads now; first use is after compute(tile0) ----
    const float4 sgB  = *reinterpret_cast<const float4*>(&sigma[io1 * NN + n0]);
    const float4 alB  = *reinterpret_cast<const float4*>(&alpha[io1 * NN + n0]);
    const float4 wB   = *reinterpret_cast<const float4*>(&w[io1 * NN + n0]);
    const float  scaB = scale[io1];
    const float  mxtB = mx_train[io1];

    float acc[OPB];
#pragma unroll
    for (int op = 0; op < OPB; ++op) acc[op] = 0.0f;

    // ---- compute tile0 (HBM latency of tile1 hides under this) ----
#pragma unroll
    for (int j = 0; j < CHI / 8; ++j) {     // 2 iters
        const int ii = iw + 8 * j;
        const float xv = xs[b * XP + ii];   // tile0: global ii == local ii
#pragma unroll
        for (int op = 0; op < OPB; ++op) {
            const float2 s2 = sc[0][ii * OPB + op];
            const float  nc = fmaf(xv, s2.x, s2.y);
            const float lof = fminf(fmaxf(floorf(nc), 0.0f), (float)LOMAX);
            const int   lo  = (int)lof;
            const float4* pp = &pr[(ii * OPB + op) * NN + lo];
#pragma unroll
            for (int k = 0; k < NW; ++k) {
                const float4 P = pp[k];
                const float zs = fmaf(xv, P.x, P.y);
                const float m  = -zs * zs;
                const float e  = EXP2F(m);
                const float u  = P.z * zs;
                const float au = fabsf(u);
                float d = fmaf(EA4, au, EA3);
                d = fmaf(d, au, EA2);
                d = fmaf(d, au, EA1);
                d = fmaf(d, au, 1.0f);
                const float rr = RCPF(d);
                const float r2 = rr * rr;
                const float r4 = r2 * r2;
                const float erfu = __builtin_copysignf(1.0f - r4, u);
                const float gg   = fmaf(e, erfu, e);
                acc[op] = fmaf(gg, P.w, acc[op]);
            }
        }
    }
    __syncthreads();    // all pr(tile0) reads done

    // ---- transform tile1 -> pr (loads already in flight) ----
    {
        const float sg[4] = {sgB.x, sgB.y, sgB.z, sgB.w};
        const float al[4] = {alB.x, alB.y, alB.z, alB.w};
        const float wv[4] = {wB.x,  wB.y,  wB.z,  wB.w};
        const float mx[4] = {mx4.x, mx4.y, mx4.z, mx4.w};
        const float sa = fabsf(scaB);
        float4* dst = &pr[(il * OPB + op_s) * NN + n0];
#pragma unroll
        for (int c = 0; c < 4; ++c) {
            const float c1s = KS * RCPF(fabsf(sg[c]) + 1e-8f);
            const float ctr = fmaf(sa, mx[c], mxtB);
            dst[c] = make_float4(c1s, -ctr * c1s, al[c] * K_A2N, wv[c]);
        }
    }
    __syncthreads();

    // ---- compute tile1 ----
#pragma unroll
    for (int j = 0; j < CHI / 8; ++j) {
        const int ii = iw + 8 * j;
        const float xv = xs[b * XP + 16 + ii];   // tile1: global ii = 16 + local
#pragma unroll
        for (int op = 0; op < OPB; ++op) {
            const float2 s2 = sc[1][ii * OPB + op];
            const float  nc = fmaf(xv, s2.x, s2.y);
            const float lof = fminf(fmaxf(floorf(nc), 0.0f), (float)LOMAX);
            const int   lo  = (int)lof;
            const float4* pp = &pr[(ii * OPB + op) * NN + lo];
#pragma unroll
            for (int k = 0; k < NW; ++k) {
                const float4 P = pp[k];
                const float zs = fmaf(xv, P.x, P.y);
                const float m  = -zs * zs;
                const float e  = EXP2F(m);
                const float u  = P.z * zs;
                const float au = fabsf(u);
                float d = fmaf(EA4, au, EA3);
                d = fmaf(d, au, EA2);
                d = fmaf(d, au, EA1);
                d = fmaf(d, au, 1.0f);
                const float rr = RCPF(d);
                const float r2 = rr * rr;
                const float r4 = r2 * r2;
                const float erfu = __builtin_copysignf(1.0f - r4, u);
                const float gg   = fmaf(e, erfu, e);
                acc[op] = fmaf(gg, P.w, acc[op]);
            }
        }
    }

    // ---- reduce over iw; store ws[qp][o][b]: 4 x 128 B contiguous rows ----
#pragma unroll
    for (int op = 0; op < OPB; ++op) red[op][iw][b] = acc[op];
    __syncthreads();
    if (tid < OPB * BB) {                   // 128
        const int op = tid >> 5;
        const int bb = tid & 31;
        float s = 0.0f;
#pragma unroll
        for (int k = 0; k < 8; ++k) s += red[op][k][bb];
        ws[qp * (OO * BB) + (o0 + op) * BB + bb] = s;
    }
}

// out[b,o] = sum_q ws[q][o][b]; reads coalesced, tiny scattered out write.
__global__ __launch_bounds__(256)
void kat_reduce(const float* __restrict__ ws, float* __restrict__ out)
{
    const int tid = threadIdx.x;
    const int o   = blockIdx.x * 8 + (tid >> 5);
    const int bb  = tid & 31;
    float s = 0.0f;
#pragma unroll
    for (int qq = 0; qq < QP; ++qq) s += ws[qq * (OO * BB) + o * BB + bb];
    out[bb * OO + o] = s;
}

extern "C" void kernel_launch(void* const* d_in, const int* in_sizes, int n_in,
                              void* d_out, int out_size, void* d_ws, size_t ws_size,
                              hipStream_t stream)
{
    const float* x        = (const float*)d_in[0];
    const float* mx_train = (const float*)d_in[1];
    const float* scale    = (const float*)d_in[2];
    const float* sigma    = (const float*)d_in[3];
    const float* alpha    = (const float*)d_in[4];
    const float* w        = (const float*)d_in[5];
    const float* mx_start = (const float*)d_in[6];
    float* ws             = (float*)d_ws;      // QP * O * B floats = 1 MB
    float* out            = (float*)d_out;

    kat_win<<<QP * NOB, 256, 0, stream>>>(x, mx_train, scale, sigma,
                                          alpha, w, mx_start, ws);
    kat_reduce<<<OO / 8, 256, 0, stream>>>(ws, out);
}

// Round 19
// 21.796 us; speedup vs baseline: 1.0279x; 1.0279x over previous
//
#include <hip/hip_runtime.h>
#include <math.h>

#define BB 32
#define II 512
#define OO 512
#define NN 16

#define NW 2            // n-window: the two nearest centers (lo = floor(nc))
#define LOMAX (NN - NW) // 14
#define QS 16           // i-split (partials in ws); ws = QS*O*B floats = 1 MB
#define CHI 32          // i's per block
#define OPB 2           // o's per block -> 128 B contiguous param segments
#define NOB (OO / OPB)  // 256 o-blocks; grid = QS*NOB = 4096

#if __has_builtin(__builtin_amdgcn_exp2f)
#define EXP2F(x) __builtin_amdgcn_exp2f(x)
#else
#define EXP2F(x) exp2f(x)
#endif
#if __has_builtin(__builtin_amdgcn_rcpf)
#define RCPF(x) __builtin_amdgcn_rcpf(x)
#else
#define RCPF(x) (1.0f / (x))
#endif

// KS = sqrt(log2 e): zs = z*KS so exp(-z^2) = exp2(-zs^2)
// K_A2N = (1/sqrt(2))/KS: u = alpha*z/sqrt(2) = (alpha*K_A2N)*zs
#define KS      1.2011224087f
#define K_A2N   0.5887050112f
// A&S 7.1.27: erf(x) = 1 - (1 + a1 x + a2 x^2 + a3 x^3 + a4 x^4)^-4, |err|<=5e-4
#define EA1 0.278393f
#define EA2 0.230389f
#define EA3 0.000972f
#define EA4 0.078108f

// R14 EXACT REVERT — the proven optimum (21.7 us, absmax 2.441e-4).
// Lineage: windowed NW=2 basis evaluation (R9), OPB=2 o-pair blocks for
// 128 B param segments (R12, -5.1 us), ws[q][o][b] coalesced partials (R14).
// Structural attempts beyond this (R13 OPB=8 bundle, R15 OPB=4, R16 2-tile
// reg prefetch, R17/R18 wave-autonomous staging) were null, regressions, or
// incorrect — the stage->barrier->compute serialization at ~50% HBM / ~50%
// VALU is the practical plateau for this op at HIP source level.
__global__ __launch_bounds__(256, 8)
void kat_win(const float* __restrict__ x,
             const float* __restrict__ mx_train,
             const float* __restrict__ scale,
             const float* __restrict__ sigma,
             const float* __restrict__ alpha,
             const float* __restrict__ w,
             const float* __restrict__ mx_start,
             float* __restrict__ ws)
{
    __shared__ float4 pr[CHI * OPB * NN];  // 16 KB [i][op][n] {c1s,c0s,a2n,w}
    __shared__ float  xs[BB * 33];         // 4.2 KB [b][ii], pitch 33
    __shared__ float2 sc[CHI * OPB];       // 512 B (inv_s15, -mxt*inv_s15)
    __shared__ float  red[OPB][8][BB];     // 2 KB

    const int bid = blockIdx.x;
    const int ob  = bid & (NOB - 1);
    const int q   = bid >> 8;
    const int o0  = ob * OPB;
    const int tid = threadIdx.x;
    const int b   = tid & 31;
    const int iw  = tid >> 5;
    const int i0  = q * CHI;

    // ---- stage x[b][i0+ii] -> xs (coalesced) ----
#pragma unroll
    for (int p = 0; p < (BB * CHI) / 256; ++p) {
        const int idx = p * 256 + tid;
        const int bb  = idx >> 5;
        const int ii  = idx & 31;
        xs[bb * 33 + ii] = x[bb * II + i0 + ii];
    }
    // ---- stage per-tuple constants: float4 per thread, 128 B/segment ----
    {
        const int il = tid >> 3;             // 0..31
        const int r  = tid & 7;              // 0..7 -> 8 float4 = 128 B per il
        const int op = r >> 2;               // 0..1
        const int n0 = (r & 3) * 4;          // 0,4,8,12
        const int io = (i0 + il) * OO + o0 + op;
        const float4 sg4 = *reinterpret_cast<const float4*>(&sigma[io * NN + n0]);
        const float4 al4 = *reinterpret_cast<const float4*>(&alpha[io * NN + n0]);
        const float4 w4  = *reinterpret_cast<const float4*>(&w[io * NN + n0]);
        const float4 mx4 = *reinterpret_cast<const float4*>(&mx_start[n0]);
        const float  sca = fabsf(scale[io]);
        const float  mxt = mx_train[io];

        const float sg[4] = {sg4.x, sg4.y, sg4.z, sg4.w};
        const float al[4] = {al4.x, al4.y, al4.z, al4.w};
        const float wv[4] = {w4.x,  w4.y,  w4.z,  w4.w};
        const float mx[4] = {mx4.x, mx4.y, mx4.z, mx4.w};
        float4* dst = &pr[(il * OPB + op) * NN + n0];
#pragma unroll
        for (int c = 0; c < 4; ++c) {
            const float c1s = KS * RCPF(fabsf(sg[c]) + 1e-8f);
            const float ctr = fmaf(sca, mx[c], mxt);
            dst[c] = make_float4(c1s, -ctr * c1s, al[c] * K_A2N, wv[c]);
        }
    }
    // ---- stage window coefs: nc = (x - mxt)*15/|s| ----
    if (tid < CHI * OPB) {
        const int ii  = tid >> 1;
        const int op  = tid & 1;
        const int io  = (i0 + ii) * OO + o0 + op;
        const float s   = fmaxf(fabsf(scale[io]), 1e-20f);
        const float inv = 15.0f * RCPF(s);
        sc[tid] = make_float2(inv, -mx_train[io] * inv);
    }
    __syncthreads();

    // ---- compute: 4 i x 2 o per thread, NW=2 window each ----
    float acc0 = 0.0f, acc1 = 0.0f;
#pragma unroll
    for (int j = 0; j < CHI / 8; ++j) {
        const int ii = iw + 8 * j;
        const float xv = xs[b * 33 + ii];
#pragma unroll
        for (int op = 0; op < OPB; ++op) {
            const float2 s2 = sc[ii * OPB + op];
            const float  nc = fmaf(xv, s2.x, s2.y);
            const float lof = fminf(fmaxf(floorf(nc), 0.0f), (float)LOMAX);
            const int   lo  = (int)lof;
            const float4* pp = &pr[(ii * OPB + op) * NN + lo];
            float a = 0.0f;
#pragma unroll
            for (int k = 0; k < NW; ++k) {
                const float4 P = pp[k];
                const float zs = fmaf(xv, P.x, P.y);     // z*sqrt(log2e)
                const float m  = -zs * zs;
                const float e  = EXP2F(m);               // exp(-z^2)
                const float u  = P.z * zs;               // alpha*z/sqrt(2)
                const float au = fabsf(u);
                float d = fmaf(EA4, au, EA3);
                d = fmaf(d, au, EA2);
                d = fmaf(d, au, EA1);
                d = fmaf(d, au, 1.0f);
                const float r  = RCPF(d);
                const float r2 = r * r;
                const float r4 = r2 * r2;
                const float erfu = __builtin_copysignf(1.0f - r4, u);
                const float gg   = fmaf(e, erfu, e);     // e*(1+erf(u))
                a = fmaf(gg, P.w, a);
            }
            if (op == 0) acc0 += a; else acc1 += a;
        }
    }

    // ---- reduce over iw; store ws[q][o][b]: 2 x 128 B contiguous rows ----
    red[0][iw][b] = acc0;
    red[1][iw][b] = acc1;
    __syncthreads();
    if (tid < OPB * BB) {
        const int op = tid >> 5;
        const int bb = tid & 31;
        float s = 0.0f;
#pragma unroll
        for (int k = 0; k < 8; ++k) s += red[op][k][bb];
        ws[q * (OO * BB) + (o0 + op) * BB + bb] = s;
    }
}

// out[b,o] = sum_q ws[q][o][b]; reads coalesced (256 B/wave/q),
// tiny (8 KB) scattered out write.
__global__ __launch_bounds__(256)
void kat_reduce(const float* __restrict__ ws, float* __restrict__ out)
{
    const int tid = threadIdx.x;
    const int o   = blockIdx.x * 8 + (tid >> 5);
    const int bb  = tid & 31;
    float s = 0.0f;
#pragma unroll
    for (int qq = 0; qq < QS; ++qq) s += ws[qq * (OO * BB) + o * BB + bb];
    out[bb * OO + o] = s;
}

extern "C" void kernel_launch(void* const* d_in, const int* in_sizes, int n_in,
                              void* d_out, int out_size, void* d_ws, size_t ws_size,
                              hipStream_t stream)
{
    const float* x        = (const float*)d_in[0];
    const float* mx_train = (const float*)d_in[1];
    const float* scale    = (const float*)d_in[2];
    const float* sigma    = (const float*)d_in[3];
    const float* alpha    = (const float*)d_in[4];
    const float* w        = (const float*)d_in[5];
    const float* mx_start = (const float*)d_in[6];
    float* ws             = (float*)d_ws;      // QS * O * B floats = 1 MB
    float* out            = (float*)d_out;

    kat_win<<<QS * NOB, 256, 0, stream>>>(x, mx_train, scale, sigma,
                                          alpha, w, mx_start, ws);
    kat_reduce<<<OO / 8, 256, 0, stream>>>(ws, out);
}